// Round 1
// baseline (977.621 us; speedup 1.0000x reference)
//
#include <hip/hip_runtime.h>

// Problem constants
#define L_SEQ   4096
#define BSZQ    8
#define NSTATE  512          // N (complex state dim); fwd for n<256, bwd for n>=256
#define HDIM    512          // H
#define ROWS    (BSZQ * L_SEQ)      // 32768
#define KC1     512          // GEMM1 K  (= H)
#define NC1     1024         // GEMM1 out cols (= 2*N, re/im interleaved)
#define KC2     1024         // GEMM2 K  (= 2*N)
#define NC2     512          // GEMM2 out cols (= H)
#define CHUNK   64
#define NCHUNK  64           // L_SEQ / CHUNK

// ---------------- lam = exp(-exp(nu_log) + i*exp(theta_log)) ----------------
__global__ __launch_bounds__(512) void lru_lam_kernel(
    const float* __restrict__ nu_log, const float* __restrict__ theta_log,
    float2* __restrict__ lam)
{
    int n = threadIdx.x;
    float mag = expf(-expf(nu_log[n]));
    float th  = expf(theta_log[n]);
    lam[n] = make_float2(mag * cosf(th), mag * sinf(th));
}

// ---------------- D[k][j]: D[2n] = C0[n,:], D[2n+1] = -C1[n,:] --------------
__global__ __launch_bounds__(256) void prep_D_kernel(
    const float* __restrict__ C, float* __restrict__ D)
{
    int idx = blockIdx.x * 256 + threadIdx.x;   // 1024*512 total
    int k = idx >> 9;
    int j = idx & 511;
    int n = k >> 1, c = k & 1;
    float v = C[((size_t)c * 512 + n) * 512 + j];
    D[idx] = c ? -v : v;
}

// ---------------- fp32 SGEMM: 128x128 tile, 8x8 micro, BK=16 ----------------
// Co[r, j] = sum_k A[r,k] * Bm[k,j];  optional row mask (zero rows l>=len[b]).
template<int KD, int ND, bool MASK>
__global__ __launch_bounds__(256) void sgemm_kernel(
    const float* __restrict__ A, const float* __restrict__ Bm,
    float* __restrict__ Co, const int* __restrict__ lengths)
{
    __shared__ float As[16][132];   // padded stride: store-transpose conflicts ~2-way
    __shared__ float Bs[16][128];
    const int tid  = threadIdx.x;
    const int row0 = blockIdx.y * 128;
    const int col0 = blockIdx.x * 128;
    const int tm = tid >> 4, tn = tid & 15;

    float acc[8][8];
#pragma unroll
    for (int i = 0; i < 8; i++)
#pragma unroll
        for (int j = 0; j < 8; j++) acc[i][j] = 0.f;

    for (int kt = 0; kt < KD; kt += 16) {
#pragma unroll
        for (int i = 0; i < 2; i++) {
            int idx = tid + i * 256;        // 0..511
            int r   = idx >> 2;             // 0..127
            int kc  = (idx & 3) << 2;       // 0,4,8,12
            float4 av = *(const float4*)(A + (size_t)(row0 + r) * KD + (kt + kc));
            As[kc + 0][r] = av.x; As[kc + 1][r] = av.y;
            As[kc + 2][r] = av.z; As[kc + 3][r] = av.w;
        }
#pragma unroll
        for (int i = 0; i < 2; i++) {
            int idx = tid + i * 256;
            int kr  = idx >> 5;             // 0..15
            int c4  = (idx & 31) << 2;      // 0..124
            *(float4*)(&Bs[kr][c4]) =
                *(const float4*)(Bm + (size_t)(kt + kr) * ND + (col0 + c4));
        }
        __syncthreads();
#pragma unroll
        for (int k = 0; k < 16; k++) {
            float a[8], b[8];
#pragma unroll
            for (int i = 0; i < 8; i++) a[i] = As[k][tm * 8 + i];
#pragma unroll
            for (int j = 0; j < 8; j++) b[j] = Bs[k][tn * 8 + j];
#pragma unroll
            for (int i = 0; i < 8; i++)
#pragma unroll
                for (int j = 0; j < 8; j++)
                    acc[i][j] = fmaf(a[i], b[j], acc[i][j]);
        }
        __syncthreads();
    }

#pragma unroll
    for (int i = 0; i < 8; i++) {
        int r = row0 + tm * 8 + i;
        bool zero = false;
        if (MASK) {
            int bb = r >> 12;               // / L_SEQ
            int l  = r & (L_SEQ - 1);
            zero = (l >= lengths[bb]);
        }
        float4 v0, v1;
        if (zero) { v0 = make_float4(0, 0, 0, 0); v1 = v0; }
        else {
            v0 = make_float4(acc[i][0], acc[i][1], acc[i][2], acc[i][3]);
            v1 = make_float4(acc[i][4], acc[i][5], acc[i][6], acc[i][7]);
        }
        float* op = Co + (size_t)r * ND + col0 + tn * 8;
        *(float4*)op       = v0;
        *(float4*)(op + 4) = v1;
    }
}

// ---------------- scan phase 1: local chunk scans (in-place on Bu) ----------
// bu layout: float2 at index (b*L + l)*512 + n. Thread n of block (b,chunk).
__global__ __launch_bounds__(512) void scan_local_kernel(
    float2* __restrict__ bu, const float2* __restrict__ lam,
    float2* __restrict__ states)
{
    int n = threadIdx.x;
    int b = blockIdx.x >> 6;
    int c = blockIdx.x & 63;
    float2 lm = lam[n];
    float xr = 0.f, xi = 0.f;
    bool fwd = (n < 256);
    int l0 = fwd ? (c * CHUNK) : (c * CHUNK + CHUNK - 1);
    float2* p = bu + ((size_t)b * L_SEQ + l0) * 512 + n;
    ptrdiff_t step = fwd ? 512 : -512;
#pragma unroll 8
    for (int t = 0; t < CHUNK; t++) {
        float2 v = *p;
        float nr = lm.x * xr - lm.y * xi + v.x;
        float ni = lm.x * xi + lm.y * xr + v.y;
        xr = nr; xi = ni;
        *p = make_float2(xr, xi);
        p += step;
    }
    states[((size_t)b * NCHUNK + c) * 512 + n] = make_float2(xr, xi);
}

// ---------------- scan phase 2: combine chunk states -> exclusive carries ---
__global__ __launch_bounds__(512) void scan_combine_kernel(
    const float2* __restrict__ states, float2* __restrict__ carries,
    const float2* __restrict__ lam)
{
    int n = threadIdx.x;
    int b = blockIdx.x;
    float2 lm = lam[n];
    // A = lam^CHUNK by repeated squaring (CHUNK = 64 = 2^6)
    float ar = lm.x, ai = lm.y;
#pragma unroll
    for (int i = 0; i < 6; i++) {
        float nr = ar * ar - ai * ai;
        ai = 2.f * ar * ai;
        ar = nr;
    }
    float cr = 0.f, ci = 0.f;
    bool fwd = (n < 256);
    if (fwd) {
        for (int c = 0; c < NCHUNK; c++) {
            size_t idx = ((size_t)b * NCHUNK + c) * 512 + n;
            carries[idx] = make_float2(cr, ci);
            float2 s = states[idx];
            float nr = ar * cr - ai * ci + s.x;
            float ni = ar * ci + ai * cr + s.y;
            cr = nr; ci = ni;
        }
    } else {
        for (int c = NCHUNK - 1; c >= 0; c--) {
            size_t idx = ((size_t)b * NCHUNK + c) * 512 + n;
            carries[idx] = make_float2(cr, ci);
            float2 s = states[idx];
            float nr = ar * cr - ai * ci + s.x;
            float ni = ar * ci + ai * cr + s.y;
            cr = nr; ci = ni;
        }
    }
}

// ---------------- scan phase 3: apply carries + final mask ------------------
__global__ __launch_bounds__(512) void scan_apply_kernel(
    float2* __restrict__ bu, const float2* __restrict__ carries,
    const float2* __restrict__ lam, const int* __restrict__ lengths)
{
    int n = threadIdx.x;
    int b = blockIdx.x >> 6;
    int c = blockIdx.x & 63;
    int len = lengths[b];
    float2 lm = lam[n];
    float2 cy = carries[((size_t)b * NCHUNK + c) * 512 + n];
    bool fwd = (n < 256);
    float pr = lm.x, pi = lm.y;            // lam^(t+1)
    int l0 = fwd ? (c * CHUNK) : (c * CHUNK + CHUNK - 1);
    int dl = fwd ? 1 : -1;
    float2* p = bu + ((size_t)b * L_SEQ + l0) * 512 + n;
    ptrdiff_t step = fwd ? 512 : -512;
    int l = l0;
#pragma unroll 8
    for (int t = 0; t < CHUNK; t++) {
        float2 v = *p;
        float xr = v.x + pr * cy.x - pi * cy.y;
        float xi = v.y + pr * cy.y + pi * cy.x;
        if (l >= len) { xr = 0.f; xi = 0.f; }
        *p = make_float2(xr, xi);
        float nr = pr * lm.x - pi * lm.y;
        pi = pr * lm.y + pi * lm.x;
        pr = nr;
        p += step; l += dl;
    }
}

// ---------------- launch ----------------------------------------------------
extern "C" void kernel_launch(void* const* d_in, const int* in_sizes, int n_in,
                              void* d_out, int out_size, void* d_ws, size_t ws_size,
                              hipStream_t stream)
{
    const float* u        = (const float*)d_in[0];   // (8,4096,512)
    const int*   lengths  = (const int*)  d_in[1];   // (8,)
    const float* nu_log   = (const float*)d_in[2];   // (512,)
    const float* theta_log= (const float*)d_in[3];   // (512,)
    const float* B        = (const float*)d_in[4];   // (512,512,2) == row-major (512 x 1024)
    const float* C        = (const float*)d_in[5];   // (2,512,512)
    float* y  = (float*)d_out;                        // (8,4096,512)
    float* ws = (float*)d_ws;

    // workspace layout (floats)
    float2* lam     = (float2*)ws;                        // 512 float2  (1024 f)
    float*  D       = ws + 1024;                          // 1024*512    (524288 f)
    float2* states  = (float2*)(ws + 1024 + 524288);      // 262144 float2
    float2* carries = states + 262144;                    // 262144 float2
    float*  bu      = ws + 1024 + 524288 + 1048576;       // 32768*1024 f (128 MB)

    lru_lam_kernel<<<1, 512, 0, stream>>>(nu_log, theta_log, lam);
    prep_D_kernel<<<2048, 256, 0, stream>>>(C, D);

    // GEMM1: Bu = u @ B  (mask rows l >= len[b])
    {
        dim3 grid(NC1 / 128, ROWS / 128);   // (8, 256)
        sgemm_kernel<KC1, NC1, true><<<grid, 256, 0, stream>>>(u, B, bu, lengths);
    }

    scan_local_kernel<<<BSZQ * NCHUNK, 512, 0, stream>>>((float2*)bu, lam, states);
    scan_combine_kernel<<<BSZQ, 512, 0, stream>>>(states, carries, lam);
    scan_apply_kernel<<<BSZQ * NCHUNK, 512, 0, stream>>>((float2*)bu, carries, lam, lengths);

    // GEMM2: y = x @ D
    {
        dim3 grid(NC2 / 128, ROWS / 128);   // (4, 256)
        sgemm_kernel<KC2, NC2, false><<<grid, 256, 0, stream>>>(bu, D, y, nullptr);
    }
}

// Round 2
// 544.444 us; speedup vs baseline: 1.7956x; 1.7956x over previous
//
#include <hip/hip_runtime.h>

// Problem constants
#define L_SEQ   4096
#define BSZQ    8
#define ROWS    (BSZQ * L_SEQ)      // 32768
#define KC1     512                 // GEMM1 K  (= H)
#define NC1     1024                // GEMM1 out cols (= 2*N interleaved re/im)
#define KC2     1024                // GEMM2 K
#define NC2     512                 // GEMM2 out cols (= H)
#define CHUNK   64
#define NCHUNK  64                  // L_SEQ / CHUNK

typedef __attribute__((ext_vector_type(8))) short bfrag;   // 8 bf16 (4 VGPRs)
typedef __attribute__((ext_vector_type(4))) float ffrag;   // 4 fp32 acc

static __device__ __forceinline__ unsigned short f2bf(float f) {
    union { float f; unsigned int u; } v; v.f = f;
    unsigned int r = v.u + 0x7fffu + ((v.u >> 16) & 1u);   // round-nearest-even
    return (unsigned short)(r >> 16);
}

// ---------------- lam = exp(-exp(nu_log) + i*exp(theta_log)) ----------------
__global__ __launch_bounds__(512) void lru_lam_kernel(
    const float* __restrict__ nu_log, const float* __restrict__ theta_log,
    float2* __restrict__ lam)
{
    int n = threadIdx.x;
    float mag = expf(-expf(nu_log[n]));
    float th  = expf(theta_log[n]);
    lam[n] = make_float2(mag * cosf(th), mag * sinf(th));
}

// ---------------- u (fp32) -> ub (bf16), 8 elems/thread ---------------------
__global__ __launch_bounds__(256) void conv_u_kernel(
    const float* __restrict__ u, unsigned short* __restrict__ ub)
{
    int idx = blockIdx.x * 256 + threadIdx.x;   // 2,097,152 total
    const float4 a = *(const float4*)(u + (size_t)idx * 8);
    const float4 b = *(const float4*)(u + (size_t)idx * 8 + 4);
    union { unsigned short s[8]; float4 f; } o;
    o.s[0] = f2bf(a.x); o.s[1] = f2bf(a.y); o.s[2] = f2bf(a.z); o.s[3] = f2bf(a.w);
    o.s[4] = f2bf(b.x); o.s[5] = f2bf(b.y); o.s[6] = f2bf(b.z); o.s[7] = f2bf(b.w);
    *(float4*)(ub + (size_t)idx * 8) = o.f;
}

// ---------------- Bt1[n2][h] = bf16(B[h][n2])  (1024 x 512) -----------------
__global__ __launch_bounds__(256) void prep_Bt_kernel(
    const float* __restrict__ B, unsigned short* __restrict__ Bt)
{
    int idx = blockIdx.x * 256 + threadIdx.x;   // 524288 total
    int n2 = idx >> 9, h = idx & 511;
    Bt[idx] = f2bf(B[(size_t)h * 1024 + n2]);
}

// ---------------- Dt[j][2n+c] = bf16((c?-1:1) * C[c][n][j])  (512 x 1024) ---
__global__ __launch_bounds__(256) void prep_Dt_kernel(
    const float* __restrict__ C, unsigned short* __restrict__ Dt)
{
    int idx = blockIdx.x * 256 + threadIdx.x;   // 524288 total
    int j = idx >> 10, k = idx & 1023;
    int n = k >> 1, c = k & 1;
    float v = C[((size_t)c * 512 + n) * 512 + j];
    Dt[idx] = f2bf(c ? -v : v);
}

// ---------------- bf16 MFMA GEMM: Co[r,j] = sum_k A[r,k] * Bt[j,k] ----------
// 128x128 block tile, 4 waves of 64x64, BK=32, 16x16x32 bf16 MFMA.
// LDS: k-plane layout, plane stride 130 float4 -> staging writes and b128
// fragment reads are bank-conflict-free (hand-checked phase-by-phase).
template<int KD, int ND, bool MASK>
__global__ __launch_bounds__(256) void mfma_gemm_kernel(
    const unsigned short* __restrict__ A,   // row-major [., KD] bf16
    const unsigned short* __restrict__ Bt,  // row-major [ND, KD] bf16
    float* __restrict__ Co, const int* __restrict__ lengths)
{
    __shared__ float4 As4[4 * 130];
    __shared__ float4 Bs4[4 * 130];
    const int tid  = threadIdx.x;
    const int row0 = blockIdx.y * 128;
    const int col0 = blockIdx.x * 128;
    const int lane = tid & 63, w = tid >> 6;
    const int q = lane >> 4, m16 = lane & 15;
    const int wr = (w >> 1) * 64, wc = (w & 1) * 64;

    ffrag acc[4][4];
#pragma unroll
    for (int i = 0; i < 4; i++)
#pragma unroll
        for (int j = 0; j < 4; j++) acc[i][j] = (ffrag)0.f;

    for (int kt = 0; kt < KD; kt += 32) {
        float4 av[2], bv[2];
#pragma unroll
        for (int i = 0; i < 2; i++) {
            int idx = tid + i * 256;         // 0..511
            int r = idx >> 2, kq = idx & 3;  // 128 rows x 4 k-quads
            av[i] = *(const float4*)(A  + (size_t)(row0 + r) * KD + kt + kq * 8);
            bv[i] = *(const float4*)(Bt + (size_t)(col0 + r) * KD + kt + kq * 8);
        }
        __syncthreads();
#pragma unroll
        for (int i = 0; i < 2; i++) {
            int idx = tid + i * 256;
            int r = idx >> 2, kq = idx & 3;
            As4[kq * 130 + r] = av[i];
            Bs4[kq * 130 + r] = bv[i];
        }
        __syncthreads();

        bfrag a[4], b[4];
#pragma unroll
        for (int ri = 0; ri < 4; ri++)
            a[ri] = *(bfrag*)&As4[q * 130 + wr + ri * 16 + m16];
#pragma unroll
        for (int ci = 0; ci < 4; ci++)
            b[ci] = *(bfrag*)&Bs4[q * 130 + wc + ci * 16 + m16];
#pragma unroll
        for (int ri = 0; ri < 4; ri++)
#pragma unroll
            for (int ci = 0; ci < 4; ci++)
                acc[ri][ci] = __builtin_amdgcn_mfma_f32_16x16x32_bf16(
                    a[ri], b[ci], acc[ri][ci], 0, 0, 0);
    }

    // Epilogue: C/D layout col = lane&15, row = (lane>>4)*4 + reg
#pragma unroll
    for (int ri = 0; ri < 4; ri++) {
#pragma unroll
        for (int r4 = 0; r4 < 4; r4++) {
            int row = row0 + wr + ri * 16 + q * 4 + r4;
            bool zero = false;
            if (MASK) {
                int bb = row >> 12;
                int l  = row & (L_SEQ - 1);
                zero = (l >= lengths[bb]);
            }
#pragma unroll
            for (int ci = 0; ci < 4; ci++) {
                int col = col0 + wc + ci * 16 + m16;
                Co[(size_t)row * ND + col] = zero ? 0.f : acc[ri][ci][r4];
            }
        }
    }
}

// ---------------- scan phase 1: local chunk scans (in-place on Bu) ----------
__global__ __launch_bounds__(512) void scan_local_kernel(
    float2* __restrict__ bu, const float2* __restrict__ lam,
    float2* __restrict__ states)
{
    int n = threadIdx.x;
    int b = blockIdx.x >> 6;
    int c = blockIdx.x & 63;
    float2 lm = lam[n];
    float xr = 0.f, xi = 0.f;
    bool fwd = (n < 256);
    int l0 = fwd ? (c * CHUNK) : (c * CHUNK + CHUNK - 1);
    float2* p = bu + ((size_t)b * L_SEQ + l0) * 512 + n;
    ptrdiff_t step = fwd ? 512 : -512;
#pragma unroll 8
    for (int t = 0; t < CHUNK; t++) {
        float2 v = *p;
        float nr = lm.x * xr - lm.y * xi + v.x;
        float ni = lm.x * xi + lm.y * xr + v.y;
        xr = nr; xi = ni;
        *p = make_float2(xr, xi);
        p += step;
    }
    states[((size_t)b * NCHUNK + c) * 512 + n] = make_float2(xr, xi);
}

// ---------------- scan phase 2: combine chunk states -> exclusive carries ---
__global__ __launch_bounds__(512) void scan_combine_kernel(
    const float2* __restrict__ states, float2* __restrict__ carries,
    const float2* __restrict__ lam)
{
    int n = threadIdx.x;
    int b = blockIdx.x;
    float2 lm = lam[n];
    float ar = lm.x, ai = lm.y;          // lam^64 by repeated squaring
#pragma unroll
    for (int i = 0; i < 6; i++) {
        float nr = ar * ar - ai * ai;
        ai = 2.f * ar * ai;
        ar = nr;
    }
    float cr = 0.f, ci = 0.f;
    bool fwd = (n < 256);
    if (fwd) {
        for (int c = 0; c < NCHUNK; c++) {
            size_t idx = ((size_t)b * NCHUNK + c) * 512 + n;
            carries[idx] = make_float2(cr, ci);
            float2 s = states[idx];
            float nr = ar * cr - ai * ci + s.x;
            float ni = ar * ci + ai * cr + s.y;
            cr = nr; ci = ni;
        }
    } else {
        for (int c = NCHUNK - 1; c >= 0; c--) {
            size_t idx = ((size_t)b * NCHUNK + c) * 512 + n;
            carries[idx] = make_float2(cr, ci);
            float2 s = states[idx];
            float nr = ar * cr - ai * ci + s.x;
            float ni = ar * ci + ai * cr + s.y;
            cr = nr; ci = ni;
        }
    }
}

// ---------------- scan phase 3: apply carries + mask -> x as bf16 -----------
__global__ __launch_bounds__(512) void scan_apply_kernel(
    const float2* __restrict__ bu, const float2* __restrict__ carries,
    const float2* __restrict__ lam, const int* __restrict__ lengths,
    unsigned int* __restrict__ xbf)   // packed (bf16 re, bf16 im) per uint
{
    int n = threadIdx.x;
    int b = blockIdx.x >> 6;
    int c = blockIdx.x & 63;
    int len = lengths[b];
    float2 lm = lam[n];
    float2 cy = carries[((size_t)b * NCHUNK + c) * 512 + n];
    bool fwd = (n < 256);
    float pr = lm.x, pi = lm.y;          // lam^(t+1)
    int l0 = fwd ? (c * CHUNK) : (c * CHUNK + CHUNK - 1);
    int dl = fwd ? 1 : -1;
    const float2* p = bu + ((size_t)b * L_SEQ + l0) * 512 + n;
    unsigned int* po = xbf + ((size_t)b * L_SEQ + l0) * 512 + n;
    ptrdiff_t step = fwd ? 512 : -512;
    int l = l0;
#pragma unroll 8
    for (int t = 0; t < CHUNK; t++) {
        float2 v = *p;
        float xr = v.x + pr * cy.x - pi * cy.y;
        float xi = v.y + pr * cy.y + pi * cy.x;
        if (l >= len) { xr = 0.f; xi = 0.f; }
        *po = (unsigned int)f2bf(xr) | ((unsigned int)f2bf(xi) << 16);
        float nr = pr * lm.x - pi * lm.y;
        pi = pr * lm.y + pi * lm.x;
        pr = nr;
        p += step; po += step; l += dl;
    }
}

// ---------------- launch ----------------------------------------------------
extern "C" void kernel_launch(void* const* d_in, const int* in_sizes, int n_in,
                              void* d_out, int out_size, void* d_ws, size_t ws_size,
                              hipStream_t stream)
{
    const float* u        = (const float*)d_in[0];   // (8,4096,512)
    const int*   lengths  = (const int*)  d_in[1];   // (8,)
    const float* nu_log   = (const float*)d_in[2];   // (512,)
    const float* theta_log= (const float*)d_in[3];   // (512,)
    const float* B        = (const float*)d_in[4];   // (512,512,2) == (512 x 1024)
    const float* C        = (const float*)d_in[5];   // (2,512,512)
    float* y = (float*)d_out;                        // (8,4096,512)

    char* w = (char*)d_ws;
    float2* lam          = (float2*)w;  w += 4096;
    float2* states       = (float2*)w;  w += (size_t)BSZQ * NCHUNK * 512 * 8;  // 2 MB
    float2* carries      = (float2*)w;  w += (size_t)BSZQ * NCHUNK * 512 * 8;  // 2 MB
    float*  bu           = (float*)w;   w += (size_t)ROWS * 1024 * 4;          // 128 MB
    unsigned short* ub   = (unsigned short*)w; w += (size_t)ROWS * 512 * 2;    // 32 MB
    unsigned int*   xbf  = (unsigned int*)w;   w += (size_t)ROWS * 512 * 4;    // 64 MB
    unsigned short* Bt1  = (unsigned short*)w; w += (size_t)NC1 * KC1 * 2;     // 1 MB
    unsigned short* Dt   = (unsigned short*)w; w += (size_t)NC2 * KC2 * 2;     // 1 MB

    lru_lam_kernel<<<1, 512, 0, stream>>>(nu_log, theta_log, lam);
    conv_u_kernel<<<8192, 256, 0, stream>>>(u, ub);
    prep_Bt_kernel<<<2048, 256, 0, stream>>>(B, Bt1);
    prep_Dt_kernel<<<2048, 256, 0, stream>>>(C, Dt);

    // GEMM1: bu = ub @ Bt1^T  (mask rows l >= len[b]), fp32 out
    {
        dim3 grid(NC1 / 128, ROWS / 128);   // (8, 256)
        mfma_gemm_kernel<KC1, NC1, true><<<grid, 256, 0, stream>>>(ub, Bt1, bu, lengths);
    }

    scan_local_kernel<<<BSZQ * NCHUNK, 512, 0, stream>>>((float2*)bu, lam, states);
    scan_combine_kernel<<<BSZQ, 512, 0, stream>>>(states, carries, lam);
    scan_apply_kernel<<<BSZQ * NCHUNK, 512, 0, stream>>>(
        (float2*)bu, carries, lam, lengths, xbf);

    // GEMM2: y = xbf @ Dt^T, fp32 out
    {
        dim3 grid(NC2 / 128, ROWS / 128);   // (4, 256)
        mfma_gemm_kernel<KC2, NC2, false><<<grid, 256, 0, stream>>>(
            (const unsigned short*)xbf, Dt, y, nullptr);
    }
}

// Round 4
// 515.053 us; speedup vs baseline: 1.8981x; 1.0571x over previous
//
#include <hip/hip_runtime.h>

// Problem constants
#define L_SEQ   4096
#define BSZQ    8
#define ROWS    (BSZQ * L_SEQ)      // 32768
#define KC1     512                 // GEMM1 K  (= H)
#define NC1     1024                // GEMM1 out cols (= 2*N interleaved re/im)
#define KC2     1024                // GEMM2 K
#define NC2     512                 // GEMM2 out cols (= H)
#define CHUNK   64
#define NCHUNK  64                  // L_SEQ / CHUNK

typedef __attribute__((ext_vector_type(8))) short bfrag;   // 8 bf16 (4 VGPRs)
typedef __attribute__((ext_vector_type(4))) float ffrag;   // 4 fp32 acc

static __device__ __forceinline__ unsigned short f2bf(float f) {
    union { float f; unsigned int u; } v; v.f = f;
    unsigned int r = v.u + 0x7fffu + ((v.u >> 16) & 1u);   // round-nearest-even
    return (unsigned short)(r >> 16);
}
static __device__ __forceinline__ unsigned int pk2(float a, float b) {
    return (unsigned int)f2bf(a) | ((unsigned int)f2bf(b) << 16);
}

// ---------------- lam = exp(-exp(nu_log) + i*exp(theta_log)) ----------------
__global__ __launch_bounds__(512) void lru_lam_kernel(
    const float* __restrict__ nu_log, const float* __restrict__ theta_log,
    float2* __restrict__ lam)
{
    int n = threadIdx.x;
    float mag = expf(-expf(nu_log[n]));
    float th  = expf(theta_log[n]);
    lam[n] = make_float2(mag * cosf(th), mag * sinf(th));
}

// ---------------- Bt[n2][h] = bf16(B[h][n2])  (1024 x 512) ------------------
__global__ __launch_bounds__(256) void prep_Bt_kernel(
    const float* __restrict__ B, unsigned short* __restrict__ Bt)
{
    int idx = blockIdx.x * 256 + threadIdx.x;   // 524288 total
    int n2 = idx >> 9, h = idx & 511;
    Bt[idx] = f2bf(B[(size_t)h * 1024 + n2]);
}

// ---------------- Dt[j][2n+c] = bf16((c?-1:1) * C[c][n][j])  (512 x 1024) ---
__global__ __launch_bounds__(256) void prep_Dt_kernel(
    const float* __restrict__ C, unsigned short* __restrict__ Dt)
{
    int idx = blockIdx.x * 256 + threadIdx.x;   // 524288 total
    int j = idx >> 10, k = idx & 1023;
    int n = k >> 1, c = k & 1;
    float v = C[((size_t)c * 512 + n) * 512 + j];
    Dt[idx] = f2bf(c ? -v : v);
}

// ---------------- bf16 MFMA GEMM: Co[r,j] = sum_k A[r,k] * Bt[j,k] ----------
// 128x128 block tile, 4 waves of 64x64, BK=32, 16x16x32 bf16 MFMA.
// CONV: A is fp32, converted to bf16 in staging. MASK: zero rows l>=len[b].
// Epilogue routed through a 32x132 LDS slab (reuses staging union) for
// coalesced float4 stores -> no partial-line write inflation.
template<int KD, int ND, bool CONV, bool MASK>
__global__ __launch_bounds__(256) void mfma_gemm_kernel(
    const void* __restrict__ Araw, const unsigned short* __restrict__ Bt,
    float* __restrict__ Co, const int* __restrict__ lengths)
{
    __shared__ __align__(16) char smem[32 * 132 * 4];   // 16896 B
    uint4* As4 = (uint4*)smem;          // 520 uint4 (k-plane stride 130)
    uint4* Bs4 = As4 + 520;             // ends at 16640 <= 16896
    float* Ts  = (float*)smem;          // 32 x 132 fp32 epilogue slab (aliases)

    const int tid  = threadIdx.x;
    const int row0 = blockIdx.y * 128;
    const int col0 = blockIdx.x * 128;
    const int lane = tid & 63, w = tid >> 6;
    const int q = lane >> 4, m16 = lane & 15;
    const int wr = (w >> 1) * 64, wc = (w & 1) * 64;

    ffrag acc[4][4];
#pragma unroll
    for (int i = 0; i < 4; i++)
#pragma unroll
        for (int j = 0; j < 4; j++) acc[i][j] = (ffrag)0.f;

    for (int kt = 0; kt < KD; kt += 32) {
        uint4 av[2], bv[2];
#pragma unroll
        for (int i = 0; i < 2; i++) {
            int idx = tid + i * 256;         // 0..511
            int r = idx >> 2, kq = idx & 3;  // 128 rows x 4 k-quads of 8
            if (CONV) {
                const float* up = (const float*)Araw + (size_t)(row0 + r) * KD + kt + kq * 8;
                float4 a0 = *(const float4*)up;
                float4 a1 = *(const float4*)(up + 4);
                av[i].x = pk2(a0.x, a0.y); av[i].y = pk2(a0.z, a0.w);
                av[i].z = pk2(a1.x, a1.y); av[i].w = pk2(a1.z, a1.w);
            } else {
                av[i] = *(const uint4*)((const unsigned short*)Araw
                        + (size_t)(row0 + r) * KD + kt + kq * 8);
            }
            bv[i] = *(const uint4*)(Bt + (size_t)(col0 + r) * KD + kt + kq * 8);
        }
        __syncthreads();
#pragma unroll
        for (int i = 0; i < 2; i++) {
            int idx = tid + i * 256;
            int r = idx >> 2, kq = idx & 3;
            As4[kq * 130 + r] = av[i];
            Bs4[kq * 130 + r] = bv[i];
        }
        __syncthreads();

        bfrag a[4], bfr[4];
#pragma unroll
        for (int ri = 0; ri < 4; ri++)
            a[ri] = *(bfrag*)&As4[q * 130 + wr + ri * 16 + m16];
#pragma unroll
        for (int ci = 0; ci < 4; ci++)
            bfr[ci] = *(bfrag*)&Bs4[q * 130 + wc + ci * 16 + m16];
#pragma unroll
        for (int ri = 0; ri < 4; ri++)
#pragma unroll
            for (int ci = 0; ci < 4; ci++)
                acc[ri][ci] = __builtin_amdgcn_mfma_f32_16x16x32_bf16(
                    a[ri], bfr[ci], acc[ri][ci], 0, 0, 0);
    }

    // Epilogue: 4 slabs of 32 rows. Wave rows = wr + ri*16 + q*4 + r4, so
    // slab g is fed by waves with wr == (g>>1)*64, using ri in {2(g&1), 2(g&1)+1}.
#pragma unroll
    for (int g = 0; g < 4; g++) {
        __syncthreads();   // protects last frag reads (g=0) / prior slab reads
        if (wr == (g >> 1) * 64) {
            int gw = g & 1;
#pragma unroll
            for (int rj = 0; rj < 2; rj++) {
                int ri = gw * 2 + rj;
#pragma unroll
                for (int r4 = 0; r4 < 4; r4++) {
                    int rsl = rj * 16 + q * 4 + r4;          // row in slab [0,32)
                    bool zero = false;
                    if (MASK) {
                        int row = row0 + g * 32 + rsl;
                        zero = ((row & (L_SEQ - 1)) >= lengths[row >> 12]);
                    }
#pragma unroll
                    for (int ci = 0; ci < 4; ci++)
                        Ts[rsl * 132 + wc + ci * 16 + m16] =
                            zero ? 0.f : acc[ri][ci][r4];
                }
            }
        }
        __syncthreads();
#pragma unroll
        for (int i = 0; i < 4; i++) {
            int flat = i * 256 + tid;           // 0..1023
            int r = flat >> 5, c4 = flat & 31;  // 32 rows x 32 float4
            float4 v = *(float4*)&Ts[r * 132 + c4 * 4];
            *(float4*)(Co + (size_t)(row0 + g * 32 + r) * ND + col0 + c4 * 4) = v;
        }
    }
}

// ---------------- scan phase 1: local chunk scans (in-place on Bu) ----------
__global__ __launch_bounds__(512) void scan_local_kernel(
    float2* __restrict__ bu, const float2* __restrict__ lam,
    float2* __restrict__ states)
{
    int n = threadIdx.x;
    int b = blockIdx.x >> 6;
    int c = blockIdx.x & 63;
    float2 lm = lam[n];
    float xr = 0.f, xi = 0.f;
    bool fwd = (n < 256);
    int l0 = fwd ? (c * CHUNK) : (c * CHUNK + CHUNK - 1);
    float2* p = bu + ((size_t)b * L_SEQ + l0) * 512 + n;
    ptrdiff_t step = fwd ? 512 : -512;
#pragma unroll 8
    for (int t = 0; t < CHUNK; t++) {
        float2 v = *p;
        float nr = lm.x * xr - lm.y * xi + v.x;
        float ni = lm.x * xi + lm.y * xr + v.y;
        xr = nr; xi = ni;
        *p = make_float2(xr, xi);
        p += step;
    }
    states[((size_t)b * NCHUNK + c) * 512 + n] = make_float2(xr, xi);
}

// ---------------- scan phase 2: combine chunk states -> exclusive carries ---
__global__ __launch_bounds__(512) void scan_combine_kernel(
    const float2* __restrict__ states, float2* __restrict__ carries,
    const float2* __restrict__ lam)
{
    int n = threadIdx.x;
    int b = blockIdx.x;
    float2 lm = lam[n];
    float ar = lm.x, ai = lm.y;          // lam^64 by 6 squarings
#pragma unroll
    for (int i = 0; i < 6; i++) {
        float nr = ar * ar - ai * ai;
        ai = 2.f * ar * ai;
        ar = nr;
    }
    float cr = 0.f, ci = 0.f;
    bool fwd = (n < 256);
    if (fwd) {
        for (int c = 0; c < NCHUNK; c++) {
            size_t idx = ((size_t)b * NCHUNK + c) * 512 + n;
            carries[idx] = make_float2(cr, ci);
            float2 s = states[idx];
            float nr = ar * cr - ai * ci + s.x;
            float ni = ar * ci + ai * cr + s.y;
            cr = nr; ci = ni;
        }
    } else {
        for (int c = NCHUNK - 1; c >= 0; c--) {
            size_t idx = ((size_t)b * NCHUNK + c) * 512 + n;
            carries[idx] = make_float2(cr, ci);
            float2 s = states[idx];
            float nr = ar * cr - ai * ci + s.x;
            float ni = ar * ci + ai * cr + s.y;
            cr = nr; ci = ni;
        }
    }
}

// ---------------- scan phase 3: apply carries + mask -> x as bf16 -----------
__global__ __launch_bounds__(512) void scan_apply_kernel(
    const float2* __restrict__ bu, const float2* __restrict__ carries,
    const float2* __restrict__ lam, const int* __restrict__ lengths,
    unsigned int* __restrict__ xbf)   // packed (bf16 re, bf16 im) per uint
{
    int n = threadIdx.x;
    int b = blockIdx.x >> 6;
    int c = blockIdx.x & 63;
    int len = lengths[b];
    float2 lm = lam[n];
    float2 cy = carries[((size_t)b * NCHUNK + c) * 512 + n];
    bool fwd = (n < 256);
    float pr = lm.x, pi = lm.y;          // lam^(t+1)
    int l0 = fwd ? (c * CHUNK) : (c * CHUNK + CHUNK - 1);
    int dl = fwd ? 1 : -1;
    const float2* p = bu + ((size_t)b * L_SEQ + l0) * 512 + n;
    unsigned int* po = xbf + ((size_t)b * L_SEQ + l0) * 512 + n;
    ptrdiff_t step = fwd ? 512 : -512;
    int l = l0;
#pragma unroll 8
    for (int t = 0; t < CHUNK; t++) {
        float2 v = *p;
        float xr = v.x + pr * cy.x - pi * cy.y;
        float xi = v.y + pr * cy.y + pi * cy.x;
        if (l >= len) { xr = 0.f; xi = 0.f; }
        *po = pk2(xr, xi);
        float nr = pr * lm.x - pi * lm.y;
        pi = pr * lm.y + pi * lm.x;
        pr = nr;
        p += step; po += step; l += dl;
    }
}

// ---------------- launch ----------------------------------------------------
extern "C" void kernel_launch(void* const* d_in, const int* in_sizes, int n_in,
                              void* d_out, int out_size, void* d_ws, size_t ws_size,
                              hipStream_t stream)
{
    const float* u        = (const float*)d_in[0];   // (8,4096,512)
    const int*   lengths  = (const int*)  d_in[1];   // (8,)
    const float* nu_log   = (const float*)d_in[2];   // (512,)
    const float* theta_log= (const float*)d_in[3];   // (512,)
    const float* B        = (const float*)d_in[4];   // (512,512,2) == (512 x 1024)
    const float* C        = (const float*)d_in[5];   // (2,512,512)
    float* y = (float*)d_out;                        // (8,4096,512)

    char* wp = (char*)d_ws;
    float2* lam     = (float2*)wp;  wp += 4096;
    float2* states  = (float2*)wp;  wp += (size_t)BSZQ * NCHUNK * 512 * 8;  // 2 MB
    float2* carries = (float2*)wp;  wp += (size_t)BSZQ * NCHUNK * 512 * 8;  // 2 MB
    float*  bu      = (float*)wp;   wp += (size_t)ROWS * 1024 * 4;          // 128 MB
    unsigned int* xbf = (unsigned int*)wp; wp += (size_t)ROWS * 512 * 4;    // 64 MB
    unsigned short* Bt = (unsigned short*)wp; wp += (size_t)NC1 * KC1 * 2;  // 1 MB
    unsigned short* Dt = (unsigned short*)wp; wp += (size_t)NC2 * KC2 * 2;  // 1 MB

    lru_lam_kernel<<<1, 512, 0, stream>>>(nu_log, theta_log, lam);
    prep_Bt_kernel<<<2048, 256, 0, stream>>>(B, Bt);
    prep_Dt_kernel<<<2048, 256, 0, stream>>>(C, Dt);

    // GEMM1: bu = bf16(u) @ Bt^T  (mask rows l >= len[b]), fp32 out
    {
        dim3 grid(NC1 / 128, ROWS / 128);   // (8, 256)
        mfma_gemm_kernel<KC1, NC1, true, true><<<grid, 256, 0, stream>>>(
            (const void*)u, Bt, bu, lengths);
    }

    scan_local_kernel<<<BSZQ * NCHUNK, 512, 0, stream>>>((float2*)bu, lam, states);
    scan_combine_kernel<<<BSZQ, 512, 0, stream>>>(states, carries, lam);
    scan_apply_kernel<<<BSZQ * NCHUNK, 512, 0, stream>>>(
        (const float2*)bu, carries, lam, lengths, xbf);

    // GEMM2: y = xbf @ Dt^T, fp32 out
    {
        dim3 grid(NC2 / 128, ROWS / 128);   // (4, 256)
        mfma_gemm_kernel<KC2, NC2, false, false><<<grid, 256, 0, stream>>>(
            (const void*)xbf, Dt, y, nullptr);
    }
}

// Round 5
// 333.598 us; speedup vs baseline: 2.9305x; 1.5439x over previous
//
#include <hip/hip_runtime.h>

// Problem constants
#define L_SEQ   4096
#define BSZQ    8
#define ROWS    (BSZQ * L_SEQ)      // 32768
#define KC1     512                 // GEMM1 K  (= H)
#define NC1     1024                // GEMM1 out cols (= 2*N interleaved re/im)
#define KC2     1024                // GEMM2 K
#define NC2     512                 // GEMM2 out cols (= H)
#define CHUNK   64
#define NCHUNK  64                  // L_SEQ / CHUNK

typedef __attribute__((ext_vector_type(8))) short bfrag;   // 8 bf16 (4 VGPRs)
typedef __attribute__((ext_vector_type(4))) float ffrag;   // 4 fp32 acc

static __device__ __forceinline__ unsigned short f2bf(float f) {
    union { float f; unsigned int u; } v; v.f = f;
    unsigned int r = v.u + 0x7fffu + ((v.u >> 16) & 1u);   // round-nearest-even
    return (unsigned short)(r >> 16);
}
static __device__ __forceinline__ unsigned int pk2(float a, float b) {
    return (unsigned int)f2bf(a) | ((unsigned int)f2bf(b) << 16);
}

// async global->LDS, 16B per lane; lds dest = wave-uniform base + lane*16
static __device__ __forceinline__ void async16(const void* g, void* l) {
    __builtin_amdgcn_global_load_lds(
        (const __attribute__((address_space(1))) unsigned int*)g,
        (__attribute__((address_space(3))) unsigned int*)l,
        16, 0, 0);
}

// ---------------- lam = exp(-exp(nu_log) + i*exp(theta_log)) ----------------
__global__ __launch_bounds__(512) void lru_lam_kernel(
    const float* __restrict__ nu_log, const float* __restrict__ theta_log,
    float2* __restrict__ lam)
{
    int n = threadIdx.x;
    float mag = expf(-expf(nu_log[n]));
    float th  = expf(theta_log[n]);
    lam[n] = make_float2(mag * cosf(th), mag * sinf(th));
}

// ------------- u (fp32) -> ub (bf16) with length mask folded in -------------
__global__ __launch_bounds__(256) void conv_mask_kernel(
    const float* __restrict__ u, const int* __restrict__ lengths,
    unsigned short* __restrict__ ub)
{
    int idx = blockIdx.x * 256 + threadIdx.x;   // 2,097,152 total (x8 elems)
    int row = idx >> 6;                         // flat row (b*L + l)
    int l = row & (L_SEQ - 1), b = row >> 12;
    bool keep = (l < lengths[b]);
    union { unsigned int s[4]; float4 f; } o;
    if (keep) {
        const float4 a = *(const float4*)(u + (size_t)idx * 8);
        const float4 c = *(const float4*)(u + (size_t)idx * 8 + 4);
        o.s[0] = pk2(a.x, a.y); o.s[1] = pk2(a.z, a.w);
        o.s[2] = pk2(c.x, c.y); o.s[3] = pk2(c.z, c.w);
    } else {
        o.s[0] = o.s[1] = o.s[2] = o.s[3] = 0u;
    }
    *(float4*)(ub + (size_t)idx * 8) = o.f;
}

// ---------------- Bt[n2][h] = bf16(B[h][n2])  (1024 x 512) ------------------
__global__ __launch_bounds__(256) void prep_Bt_kernel(
    const float* __restrict__ B, unsigned short* __restrict__ Bt)
{
    int idx = blockIdx.x * 256 + threadIdx.x;   // 524288 total
    int n2 = idx >> 9, h = idx & 511;
    Bt[idx] = f2bf(B[(size_t)h * 1024 + n2]);
}

// ---------------- Dt[j][2n+c] = bf16((c?-1:1) * C[c][n][j])  (512 x 1024) ---
__global__ __launch_bounds__(256) void prep_Dt_kernel(
    const float* __restrict__ C, unsigned short* __restrict__ Dt)
{
    int idx = blockIdx.x * 256 + threadIdx.x;   // 524288 total
    int j = idx >> 10, k = idx & 1023;
    int n = k >> 1, c = k & 1;
    float v = C[((size_t)c * 512 + n) * 512 + j];
    Dt[idx] = f2bf(c ? -v : v);
}

// ---------------- bf16 MFMA GEMM (m97-style async staging) ------------------
// Co[r,j] = sum_k A[r,k] * Bt[j,k].  128x128 tile, 4 waves x 64x64, BK=32.
// LDS tiles: unpadded [row][k] bf16 (8KB each), filled by global_load_lds x16.
// Slot t (0..511): row = t>>2, k-quad = t&3 (16B each); wave w stages slots
// [i*256 + w*64, +64) so lds base is wave-uniform and lane lands at its slot.
template<int KD, int ND>
__global__ __launch_bounds__(256) void mfma_gemm_async(
    const unsigned short* __restrict__ A,   // row-major [., KD] bf16
    const unsigned short* __restrict__ Bt,  // row-major [ND, KD] bf16
    float* __restrict__ Co)
{
    __shared__ uint4 As[512];
    __shared__ uint4 Bs[512];
    const int tid  = threadIdx.x;
    const int row0 = blockIdx.y * 128;
    const int col0 = blockIdx.x * 128;
    const int lane = tid & 63, w = tid >> 6;
    const int q = lane >> 4, m16 = lane & 15;
    const int wr = (w >> 1) * 64, wc = (w & 1) * 64;

    ffrag acc[4][4];
#pragma unroll
    for (int i = 0; i < 4; i++)
#pragma unroll
        for (int j = 0; j < 4; j++) acc[i][j] = (ffrag)0.f;

    for (int kt = 0; kt < KD; kt += 32) {
#pragma unroll
        for (int i = 0; i < 2; i++) {
            int t = i * 256 + w * 64 + lane;     // slot index
            int r = t >> 2, kq = t & 3;
            async16(A  + (size_t)(row0 + r) * KD + kt + kq * 8, &As[i * 256 + w * 64]);
            async16(Bt + (size_t)(col0 + r) * KD + kt + kq * 8, &Bs[i * 256 + w * 64]);
        }
        __syncthreads();

        bfrag a[4], b[4];
#pragma unroll
        for (int ri = 0; ri < 4; ri++)
            a[ri] = *(bfrag*)&As[(wr + ri * 16 + m16) * 4 + q];
#pragma unroll
        for (int ci = 0; ci < 4; ci++)
            b[ci] = *(bfrag*)&Bs[(wc + ci * 16 + m16) * 4 + q];
#pragma unroll
        for (int ri = 0; ri < 4; ri++)
#pragma unroll
            for (int ci = 0; ci < 4; ci++)
                acc[ri][ci] = __builtin_amdgcn_mfma_f32_16x16x32_bf16(
                    a[ri], b[ci], acc[ri][ci], 0, 0, 0);
        __syncthreads();
    }

    // Epilogue: C/D layout col = lane&15, row = (lane>>4)*4 + reg.
    // Per (ri,r4,q): 16 lanes store 16 consecutive dwords = one 64B line.
#pragma unroll
    for (int ri = 0; ri < 4; ri++)
#pragma unroll
        for (int r4 = 0; r4 < 4; r4++) {
            int row = row0 + wr + ri * 16 + q * 4 + r4;
#pragma unroll
            for (int ci = 0; ci < 4; ci++) {
                int col = col0 + wc + ci * 16 + m16;
                Co[(size_t)row * ND + col] = acc[ri][ci][r4];
            }
        }
}

// ---------------- scan phase 1: local chunk scans (in-place on Bu) ----------
__global__ __launch_bounds__(512) void scan_local_kernel(
    float2* __restrict__ bu, const float2* __restrict__ lam,
    float2* __restrict__ states)
{
    int n = threadIdx.x;
    int b = blockIdx.x >> 6;
    int c = blockIdx.x & 63;
    float2 lm = lam[n];
    float xr = 0.f, xi = 0.f;
    bool fwd = (n < 256);
    int l0 = fwd ? (c * CHUNK) : (c * CHUNK + CHUNK - 1);
    float2* p = bu + ((size_t)b * L_SEQ + l0) * 512 + n;
    ptrdiff_t step = fwd ? 512 : -512;
#pragma unroll 8
    for (int t = 0; t < CHUNK; t++) {
        float2 v = *p;
        float nr = lm.x * xr - lm.y * xi + v.x;
        float ni = lm.x * xi + lm.y * xr + v.y;
        xr = nr; xi = ni;
        *p = make_float2(xr, xi);
        p += step;
    }
    states[((size_t)b * NCHUNK + c) * 512 + n] = make_float2(xr, xi);
}

// ---------------- scan phase 2: combine chunk states -> exclusive carries ---
__global__ __launch_bounds__(512) void scan_combine_kernel(
    const float2* __restrict__ states, float2* __restrict__ carries,
    const float2* __restrict__ lam)
{
    int n = threadIdx.x;
    int b = blockIdx.x;
    float2 lm = lam[n];
    float ar = lm.x, ai = lm.y;          // lam^64 by 6 squarings
#pragma unroll
    for (int i = 0; i < 6; i++) {
        float nr = ar * ar - ai * ai;
        ai = 2.f * ar * ai;
        ar = nr;
    }
    float cr = 0.f, ci = 0.f;
    bool fwd = (n < 256);
    if (fwd) {
        for (int c = 0; c < NCHUNK; c++) {
            size_t idx = ((size_t)b * NCHUNK + c) * 512 + n;
            carries[idx] = make_float2(cr, ci);
            float2 s = states[idx];
            float nr = ar * cr - ai * ci + s.x;
            float ni = ar * ci + ai * cr + s.y;
            cr = nr; ci = ni;
        }
    } else {
        for (int c = NCHUNK - 1; c >= 0; c--) {
            size_t idx = ((size_t)b * NCHUNK + c) * 512 + n;
            carries[idx] = make_float2(cr, ci);
            float2 s = states[idx];
            float nr = ar * cr - ai * ci + s.x;
            float ni = ar * ci + ai * cr + s.y;
            cr = nr; ci = ni;
        }
    }
}

// ---------------- scan phase 3: apply carries + mask -> x as bf16 -----------
__global__ __launch_bounds__(512) void scan_apply_kernel(
    const float2* __restrict__ bu, const float2* __restrict__ carries,
    const float2* __restrict__ lam, const int* __restrict__ lengths,
    unsigned int* __restrict__ xbf)   // packed (bf16 re, bf16 im) per uint
{
    int n = threadIdx.x;
    int b = blockIdx.x >> 6;
    int c = blockIdx.x & 63;
    int len = lengths[b];
    float2 lm = lam[n];
    float2 cy = carries[((size_t)b * NCHUNK + c) * 512 + n];
    bool fwd = (n < 256);
    float pr = lm.x, pi = lm.y;          // lam^(t+1)
    int l0 = fwd ? (c * CHUNK) : (c * CHUNK + CHUNK - 1);
    int dl = fwd ? 1 : -1;
    const float2* p = bu + ((size_t)b * L_SEQ + l0) * 512 + n;
    unsigned int* po = xbf + ((size_t)b * L_SEQ + l0) * 512 + n;
    ptrdiff_t step = fwd ? 512 : -512;
    int l = l0;
#pragma unroll 8
    for (int t = 0; t < CHUNK; t++) {
        float2 v = *p;
        float xr = v.x + pr * cy.x - pi * cy.y;
        float xi = v.y + pr * cy.y + pi * cy.x;
        if (l >= len) { xr = 0.f; xi = 0.f; }
        *po = pk2(xr, xi);
        float nr = pr * lm.x - pi * lm.y;
        pi = pr * lm.y + pi * lm.x;
        pr = nr;
        p += step; po += step; l += dl;
    }
}

// ---------------- launch ----------------------------------------------------
extern "C" void kernel_launch(void* const* d_in, const int* in_sizes, int n_in,
                              void* d_out, int out_size, void* d_ws, size_t ws_size,
                              hipStream_t stream)
{
    const float* u        = (const float*)d_in[0];   // (8,4096,512)
    const int*   lengths  = (const int*)  d_in[1];   // (8,)
    const float* nu_log   = (const float*)d_in[2];   // (512,)
    const float* theta_log= (const float*)d_in[3];   // (512,)
    const float* B        = (const float*)d_in[4];   // (512,512,2) == (512 x 1024)
    const float* C        = (const float*)d_in[5];   // (2,512,512)
    float* y = (float*)d_out;                        // (8,4096,512)

    char* wp = (char*)d_ws;
    float2* lam     = (float2*)wp;  wp += 4096;
    float2* states  = (float2*)wp;  wp += (size_t)BSZQ * NCHUNK * 512 * 8;  // 2 MB
    float2* carries = (float2*)wp;  wp += (size_t)BSZQ * NCHUNK * 512 * 8;  // 2 MB
    float*  bu      = (float*)wp;   wp += (size_t)ROWS * 1024 * 4;          // 128 MB
    unsigned short* ub = (unsigned short*)wp; wp += (size_t)ROWS * 512 * 2; // 32 MB
    unsigned int* xbf = (unsigned int*)wp; wp += (size_t)ROWS * 512 * 4;    // 64 MB
    unsigned short* Bt = (unsigned short*)wp; wp += (size_t)NC1 * KC1 * 2;  // 1 MB
    unsigned short* Dt = (unsigned short*)wp; wp += (size_t)NC2 * KC2 * 2;  // 1 MB

    lru_lam_kernel<<<1, 512, 0, stream>>>(nu_log, theta_log, lam);
    conv_mask_kernel<<<8192, 256, 0, stream>>>(u, lengths, ub);
    prep_Bt_kernel<<<2048, 256, 0, stream>>>(B, Bt);
    prep_Dt_kernel<<<2048, 256, 0, stream>>>(C, Dt);

    // GEMM1: bu = ub @ Bt^T (mask already folded into ub), fp32 out
    {
        dim3 grid(NC1 / 128, ROWS / 128);   // (8, 256)
        mfma_gemm_async<KC1, NC1><<<grid, 256, 0, stream>>>(ub, Bt, bu);
    }

    scan_local_kernel<<<BSZQ * NCHUNK, 512, 0, stream>>>((float2*)bu, lam, states);
    scan_combine_kernel<<<BSZQ, 512, 0, stream>>>(states, carries, lam);
    scan_apply_kernel<<<BSZQ * NCHUNK, 512, 0, stream>>>(
        (const float2*)bu, carries, lam, lengths, xbf);

    // GEMM2: y = xbf @ Dt^T, fp32 out
    {
        dim3 grid(NC2 / 128, ROWS / 128);   // (4, 256)
        mfma_gemm_async<KC2, NC2><<<grid, 256, 0, stream>>>(
            (const unsigned short*)xbf, Dt, y);
    }
}

// Round 6
// 315.680 us; speedup vs baseline: 3.0969x; 1.0568x over previous
//
#include <hip/hip_runtime.h>

// Problem constants
#define L_SEQ   4096
#define BSZQ    8
#define ROWS    (BSZQ * L_SEQ)      // 32768
#define KC1     512                 // GEMM1 K  (= H)
#define NC1     1024                // GEMM1 out cols (= 2*N interleaved re/im)
#define KC2     1024                // GEMM2 K
#define NC2     512                 // GEMM2 out cols (= H)
#define CHUNK   64
#define NCHUNK  64                  // L_SEQ / CHUNK

typedef __attribute__((ext_vector_type(8))) short bfrag;   // 8 bf16 (4 VGPRs)
typedef __attribute__((ext_vector_type(4))) float ffrag;   // 4 fp32 acc

static __device__ __forceinline__ unsigned short f2bf(float f) {
    union { float f; unsigned int u; } v; v.f = f;
    unsigned int r = v.u + 0x7fffu + ((v.u >> 16) & 1u);   // round-nearest-even
    return (unsigned short)(r >> 16);
}
static __device__ __forceinline__ unsigned int pk2(float a, float b) {
    return (unsigned int)f2bf(a) | ((unsigned int)f2bf(b) << 16);
}
static __device__ __forceinline__ float2 unpk2(unsigned int u) {
    union { unsigned int u; float f; } a, b;
    a.u = u << 16;
    b.u = u & 0xffff0000u;
    return make_float2(a.f, b.f);
}

// async global->LDS, 16B per lane; lds dest = wave-uniform base + lane*16
static __device__ __forceinline__ void async16(const void* g, void* l) {
    __builtin_amdgcn_global_load_lds(
        (const __attribute__((address_space(1))) unsigned int*)g,
        (__attribute__((address_space(3))) unsigned int*)l,
        16, 0, 0);
}

// ---------------- lam = exp(-exp(nu_log) + i*exp(theta_log)) ----------------
__global__ __launch_bounds__(512) void lru_lam_kernel(
    const float* __restrict__ nu_log, const float* __restrict__ theta_log,
    float2* __restrict__ lam)
{
    int n = threadIdx.x;
    float mag = expf(-expf(nu_log[n]));
    float th  = expf(theta_log[n]);
    lam[n] = make_float2(mag * cosf(th), mag * sinf(th));
}

// ------------- u (fp32) -> ub (bf16) with length mask folded in -------------
__global__ __launch_bounds__(256) void conv_mask_kernel(
    const float* __restrict__ u, const int* __restrict__ lengths,
    unsigned short* __restrict__ ub)
{
    int idx = blockIdx.x * 256 + threadIdx.x;   // 2,097,152 total (x8 elems)
    int row = idx >> 6;                         // flat row (b*L + l)
    int l = row & (L_SEQ - 1), b = row >> 12;
    bool keep = (l < lengths[b]);
    union { unsigned int s[4]; float4 f; } o;
    if (keep) {
        const float4 a = *(const float4*)(u + (size_t)idx * 8);
        const float4 c = *(const float4*)(u + (size_t)idx * 8 + 4);
        o.s[0] = pk2(a.x, a.y); o.s[1] = pk2(a.z, a.w);
        o.s[2] = pk2(c.x, c.y); o.s[3] = pk2(c.z, c.w);
    } else {
        o.s[0] = o.s[1] = o.s[2] = o.s[3] = 0u;
    }
    *(float4*)(ub + (size_t)idx * 8) = o.f;
}

// ---------------- Bt[n2][h] = bf16(B[h][n2])  (1024 x 512) ------------------
__global__ __launch_bounds__(256) void prep_Bt_kernel(
    const float* __restrict__ B, unsigned short* __restrict__ Bt)
{
    int idx = blockIdx.x * 256 + threadIdx.x;   // 524288 total
    int n2 = idx >> 9, h = idx & 511;
    Bt[idx] = f2bf(B[(size_t)h * 1024 + n2]);
}

// ---------------- Dt[j][2n+c] = bf16((c?-1:1) * C[c][n][j])  (512 x 1024) ---
__global__ __launch_bounds__(256) void prep_Dt_kernel(
    const float* __restrict__ C, unsigned short* __restrict__ Dt)
{
    int idx = blockIdx.x * 256 + threadIdx.x;   // 524288 total
    int j = idx >> 10, k = idx & 1023;
    int n = k >> 1, c = k & 1;
    float v = C[((size_t)c * 512 + n) * 512 + j];
    Dt[idx] = f2bf(c ? -v : v);
}

// ---------------- bf16 MFMA GEMM (m97-style async staging) ------------------
// Co[r,j] = sum_k A[r,k] * Bt[j,k].  128x128 tile, 4 waves x 64x64, BK=32.
// Grid: x = row block (256), y = col block -> blocks sharing a row-block are
// 256 apart in dispatch order => same XCD (round-robin %8) => A row-tile is
// fetched into exactly one XCD's L2.
template<int KD, int ND>
__global__ __launch_bounds__(256) void mfma_gemm_async(
    const unsigned short* __restrict__ A,   // row-major [., KD] bf16
    const unsigned short* __restrict__ Bt,  // row-major [ND, KD] bf16
    float* __restrict__ Co)
{
    __shared__ uint4 As[512];
    __shared__ uint4 Bs[512];
    const int tid  = threadIdx.x;
    const int row0 = blockIdx.x * 128;
    const int col0 = blockIdx.y * 128;
    const int lane = tid & 63, w = tid >> 6;
    const int q = lane >> 4, m16 = lane & 15;
    const int wr = (w >> 1) * 64, wc = (w & 1) * 64;

    ffrag acc[4][4];
#pragma unroll
    for (int i = 0; i < 4; i++)
#pragma unroll
        for (int j = 0; j < 4; j++) acc[i][j] = (ffrag)0.f;

    for (int kt = 0; kt < KD; kt += 32) {
#pragma unroll
        for (int i = 0; i < 2; i++) {
            int t = i * 256 + w * 64 + lane;     // slot index
            int r = t >> 2, kq = t & 3;
            async16(A  + (size_t)(row0 + r) * KD + kt + kq * 8, &As[i * 256 + w * 64]);
            async16(Bt + (size_t)(col0 + r) * KD + kt + kq * 8, &Bs[i * 256 + w * 64]);
        }
        __syncthreads();

        bfrag a[4], b[4];
#pragma unroll
        for (int ri = 0; ri < 4; ri++)
            a[ri] = *(bfrag*)&As[(wr + ri * 16 + m16) * 4 + q];
#pragma unroll
        for (int ci = 0; ci < 4; ci++)
            b[ci] = *(bfrag*)&Bs[(wc + ci * 16 + m16) * 4 + q];
#pragma unroll
        for (int ri = 0; ri < 4; ri++)
#pragma unroll
            for (int ci = 0; ci < 4; ci++)
                acc[ri][ci] = __builtin_amdgcn_mfma_f32_16x16x32_bf16(
                    a[ri], b[ci], acc[ri][ci], 0, 0, 0);
        __syncthreads();
    }

    // Epilogue: C/D layout col = lane&15, row = (lane>>4)*4 + reg.
    // Per (ri,r4,q): 16 lanes store 16 consecutive dwords = one 64B line.
#pragma unroll
    for (int ri = 0; ri < 4; ri++)
#pragma unroll
        for (int r4 = 0; r4 < 4; r4++) {
            int row = row0 + wr + ri * 16 + q * 4 + r4;
#pragma unroll
            for (int ci = 0; ci < 4; ci++) {
                int col = col0 + wc + ci * 16 + m16;
                Co[(size_t)row * ND + col] = acc[ri][ci][r4];
            }
        }
}

// ------- scan phase 1: local chunk scans, fp32 in -> packed bf16 out --------
__global__ __launch_bounds__(512) void scan_local_kernel(
    const float2* __restrict__ bu, const float2* __restrict__ lam,
    unsigned int* __restrict__ buloc, float2* __restrict__ states)
{
    int n = threadIdx.x;
    int b = blockIdx.x >> 6;
    int c = blockIdx.x & 63;
    float2 lm = lam[n];
    float xr = 0.f, xi = 0.f;
    bool fwd = (n < 256);
    int l0 = fwd ? (c * CHUNK) : (c * CHUNK + CHUNK - 1);
    const float2* p = bu + ((size_t)b * L_SEQ + l0) * 512 + n;
    unsigned int* po = buloc + ((size_t)b * L_SEQ + l0) * 512 + n;
    ptrdiff_t step = fwd ? 512 : -512;
#pragma unroll 8
    for (int t = 0; t < CHUNK; t++) {
        float2 v = *p;
        float nr = lm.x * xr - lm.y * xi + v.x;
        float ni = lm.x * xi + lm.y * xr + v.y;
        xr = nr; xi = ni;
        *po = pk2(xr, xi);
        p += step; po += step;
    }
    states[((size_t)b * NCHUNK + c) * 512 + n] = make_float2(xr, xi);
}

// ---------------- scan phase 2: combine chunk states -> exclusive carries ---
__global__ __launch_bounds__(512) void scan_combine_kernel(
    const float2* __restrict__ states, float2* __restrict__ carries,
    const float2* __restrict__ lam)
{
    int n = threadIdx.x;
    int b = blockIdx.x;
    float2 lm = lam[n];
    float ar = lm.x, ai = lm.y;          // lam^64 by 6 squarings
#pragma unroll
    for (int i = 0; i < 6; i++) {
        float nr = ar * ar - ai * ai;
        ai = 2.f * ar * ai;
        ar = nr;
    }
    float cr = 0.f, ci = 0.f;
    bool fwd = (n < 256);
    if (fwd) {
        for (int c = 0; c < NCHUNK; c++) {
            size_t idx = ((size_t)b * NCHUNK + c) * 512 + n;
            carries[idx] = make_float2(cr, ci);
            float2 s = states[idx];
            float nr = ar * cr - ai * ci + s.x;
            float ni = ar * ci + ai * cr + s.y;
            cr = nr; ci = ni;
        }
    } else {
        for (int c = NCHUNK - 1; c >= 0; c--) {
            size_t idx = ((size_t)b * NCHUNK + c) * 512 + n;
            carries[idx] = make_float2(cr, ci);
            float2 s = states[idx];
            float nr = ar * cr - ai * ci + s.x;
            float ni = ar * ci + ai * cr + s.y;
            cr = nr; ci = ni;
        }
    }
}

// -------- scan phase 3: apply carries + mask, IN PLACE on packed buloc ------
__global__ __launch_bounds__(512) void scan_apply_kernel(
    unsigned int* __restrict__ buloc, const float2* __restrict__ carries,
    const float2* __restrict__ lam, const int* __restrict__ lengths)
{
    int n = threadIdx.x;
    int b = blockIdx.x >> 6;
    int c = blockIdx.x & 63;
    int len = lengths[b];
    float2 lm = lam[n];
    float2 cy = carries[((size_t)b * NCHUNK + c) * 512 + n];
    bool fwd = (n < 256);
    float pr = lm.x, pi = lm.y;          // lam^(t+1)
    int l0 = fwd ? (c * CHUNK) : (c * CHUNK + CHUNK - 1);
    int dl = fwd ? 1 : -1;
    unsigned int* p = buloc + ((size_t)b * L_SEQ + l0) * 512 + n;
    ptrdiff_t step = fwd ? 512 : -512;
    int l = l0;
#pragma unroll 8
    for (int t = 0; t < CHUNK; t++) {
        float2 v = unpk2(*p);
        float xr = v.x + pr * cy.x - pi * cy.y;
        float xi = v.y + pr * cy.y + pi * cy.x;
        if (l >= len) { xr = 0.f; xi = 0.f; }
        *p = pk2(xr, xi);
        float nr = pr * lm.x - pi * lm.y;
        pi = pr * lm.y + pi * lm.x;
        pr = nr;
        p += step; l += dl;
    }
}

// ---------------- launch ----------------------------------------------------
extern "C" void kernel_launch(void* const* d_in, const int* in_sizes, int n_in,
                              void* d_out, int out_size, void* d_ws, size_t ws_size,
                              hipStream_t stream)
{
    const float* u        = (const float*)d_in[0];   // (8,4096,512)
    const int*   lengths  = (const int*)  d_in[1];   // (8,)
    const float* nu_log   = (const float*)d_in[2];   // (512,)
    const float* theta_log= (const float*)d_in[3];   // (512,)
    const float* B        = (const float*)d_in[4];   // (512,512,2) == (512 x 1024)
    const float* C        = (const float*)d_in[5];   // (2,512,512)
    float* y = (float*)d_out;                        // (8,4096,512)

    char* wp = (char*)d_ws;
    float2* lam     = (float2*)wp;  wp += 4096;
    float2* states  = (float2*)wp;  wp += (size_t)BSZQ * NCHUNK * 512 * 8;  // 2 MB
    float2* carries = (float2*)wp;  wp += (size_t)BSZQ * NCHUNK * 512 * 8;  // 2 MB
    float*  bu      = (float*)wp;   wp += (size_t)ROWS * 1024 * 4;          // 128 MB
    unsigned short* ub = (unsigned short*)wp; wp += (size_t)ROWS * 512 * 2; // 32 MB
    unsigned int* buloc = (unsigned int*)wp;  wp += (size_t)ROWS * 512 * 4; // 64 MB
    unsigned short* Bt = (unsigned short*)wp; wp += (size_t)NC1 * KC1 * 2;  // 1 MB
    unsigned short* Dt = (unsigned short*)wp; wp += (size_t)NC2 * KC2 * 2;  // 1 MB

    lru_lam_kernel<<<1, 512, 0, stream>>>(nu_log, theta_log, lam);
    conv_mask_kernel<<<8192, 256, 0, stream>>>(u, lengths, ub);
    prep_Bt_kernel<<<2048, 256, 0, stream>>>(B, Bt);
    prep_Dt_kernel<<<2048, 256, 0, stream>>>(C, Dt);

    // GEMM1: bu = ub @ Bt^T (mask already folded into ub), fp32 out
    {
        dim3 grid(ROWS / 128, NC1 / 128);   // (256, 8) row-major for XCD reuse
        mfma_gemm_async<KC1, NC1><<<grid, 256, 0, stream>>>(ub, Bt, bu);
    }

    scan_local_kernel<<<BSZQ * NCHUNK, 512, 0, stream>>>(
        (const float2*)bu, lam, buloc, states);
    scan_combine_kernel<<<BSZQ, 512, 0, stream>>>(states, carries, lam);
    scan_apply_kernel<<<BSZQ * NCHUNK, 512, 0, stream>>>(
        buloc, carries, lam, lengths);

    // GEMM2: y = buloc @ Dt^T, fp32 out
    {
        dim3 grid(ROWS / 128, NC2 / 128);   // (256, 4)
        mfma_gemm_async<KC2, NC2><<<grid, 256, 0, stream>>>(
            (const unsigned short*)buloc, Dt, y);
    }
}

// Round 7
// 296.009 us; speedup vs baseline: 3.3027x; 1.0665x over previous
//
#include <hip/hip_runtime.h>

// Problem constants
#define L_SEQ   4096
#define BSZQ    8
#define ROWS    (BSZQ * L_SEQ)      // 32768
#define KC1     512                 // GEMM1 K  (= H)
#define NC1     1024                // GEMM1 out cols (= 2*N interleaved re/im)
#define KC2     1024                // GEMM2 K
#define NC2     512                 // GEMM2 out cols (= H)
#define CHUNK   64
#define NCHUNK  64                  // L_SEQ / CHUNK

typedef __attribute__((ext_vector_type(8))) short bfrag;   // 8 bf16 (4 VGPRs)
typedef __attribute__((ext_vector_type(4))) float ffrag;   // 4 fp32 acc

static __device__ __forceinline__ unsigned short f2bf(float f) {
    union { float f; unsigned int u; } v; v.f = f;
    unsigned int r = v.u + 0x7fffu + ((v.u >> 16) & 1u);   // round-nearest-even
    return (unsigned short)(r >> 16);
}
static __device__ __forceinline__ unsigned int pk2(float a, float b) {
    return (unsigned int)f2bf(a) | ((unsigned int)f2bf(b) << 16);
}
static __device__ __forceinline__ float2 unpk2(unsigned int u) {
    union { unsigned int u; float f; } a, b;
    a.u = u << 16;
    b.u = u & 0xffff0000u;
    return make_float2(a.f, b.f);
}

// async global->LDS, 16B per lane; lds dest = wave-uniform base + lane*16
static __device__ __forceinline__ void async16(const void* g, void* l) {
    __builtin_amdgcn_global_load_lds(
        (const __attribute__((address_space(1))) unsigned int*)g,
        (__attribute__((address_space(3))) unsigned int*)l,
        16, 0, 0);
}

// ---------------- lam = exp(-exp(nu_log) + i*exp(theta_log)) ----------------
__global__ __launch_bounds__(512) void lru_lam_kernel(
    const float* __restrict__ nu_log, const float* __restrict__ theta_log,
    float2* __restrict__ lam)
{
    int n = threadIdx.x;
    float mag = expf(-expf(nu_log[n]));
    float th  = expf(theta_log[n]);
    lam[n] = make_float2(mag * cosf(th), mag * sinf(th));
}

// ------------- u (fp32) -> ub (bf16) with length mask folded in -------------
__global__ __launch_bounds__(256) void conv_mask_kernel(
    const float* __restrict__ u, const int* __restrict__ lengths,
    unsigned short* __restrict__ ub)
{
    int idx = blockIdx.x * 256 + threadIdx.x;   // 2,097,152 total (x8 elems)
    int row = idx >> 6;                         // flat row (b*L + l)
    int l = row & (L_SEQ - 1), b = row >> 12;
    bool keep = (l < lengths[b]);
    union { unsigned int s[4]; float4 f; } o;
    if (keep) {
        const float4 a = *(const float4*)(u + (size_t)idx * 8);
        const float4 c = *(const float4*)(u + (size_t)idx * 8 + 4);
        o.s[0] = pk2(a.x, a.y); o.s[1] = pk2(a.z, a.w);
        o.s[2] = pk2(c.x, c.y); o.s[3] = pk2(c.z, c.w);
    } else {
        o.s[0] = o.s[1] = o.s[2] = o.s[3] = 0u;
    }
    *(float4*)(ub + (size_t)idx * 8) = o.f;
}

// ---------------- Bt[n2][h] = bf16(B[h][n2])  (1024 x 512) ------------------
__global__ __launch_bounds__(256) void prep_Bt_kernel(
    const float* __restrict__ B, unsigned short* __restrict__ Bt)
{
    int idx = blockIdx.x * 256 + threadIdx.x;   // 524288 total
    int n2 = idx >> 9, h = idx & 511;
    Bt[idx] = f2bf(B[(size_t)h * 1024 + n2]);
}

// ---------------- Dt[j][2n+c] = bf16((c?-1:1) * C[c][n][j])  (512 x 1024) ---
__global__ __launch_bounds__(256) void prep_Dt_kernel(
    const float* __restrict__ C, unsigned short* __restrict__ Dt)
{
    int idx = blockIdx.x * 256 + threadIdx.x;   // 524288 total
    int j = idx >> 10, k = idx & 1023;
    int n = k >> 1, c = k & 1;
    float v = C[((size_t)c * 512 + n) * 512 + j];
    Dt[idx] = f2bf(c ? -v : v);
}

// ---------------- bf16 MFMA GEMM (m97-style async staging) ------------------
// Co[r,j] = sum_k A[r,k] * Bt[j,k].  128x128 tile, 4 waves x 64x64, BK=32.
// Grid: x = row block, y = col block (XCD round-robin keeps a row-block's
// col-blocks on one XCD -> A row-tile fetched once per XCD).
// BF16OUT: epilogue routes through an LDS slab (aliases staging LDS) and
// stores packed (re,im) bf16 uints, 256B contiguous per wave.
template<int KD, int ND, bool BF16OUT>
__global__ __launch_bounds__(256) void mfma_gemm_async(
    const unsigned short* __restrict__ A,   // row-major [., KD] bf16
    const unsigned short* __restrict__ Bt,  // row-major [ND, KD] bf16
    void* __restrict__ Co)
{
    __shared__ __align__(16) char smem[32 * 132 * 4];   // 16896 B
    uint4* As = (uint4*)smem;          // 512 uint4 (8 KB)
    uint4* Bs = As + 512;              // 512 uint4 (8 KB), ends 16384
    float* Ts = (float*)smem;          // 32 x 132 fp32 slab (aliases, BF16OUT)

    const int tid  = threadIdx.x;
    const int row0 = blockIdx.x * 128;
    const int col0 = blockIdx.y * 128;
    const int lane = tid & 63, w = tid >> 6;
    const int q = lane >> 4, m16 = lane & 15;
    const int wr = (w >> 1) * 64, wc = (w & 1) * 64;

    ffrag acc[4][4];
#pragma unroll
    for (int i = 0; i < 4; i++)
#pragma unroll
        for (int j = 0; j < 4; j++) acc[i][j] = (ffrag)0.f;

    for (int kt = 0; kt < KD; kt += 32) {
#pragma unroll
        for (int i = 0; i < 2; i++) {
            int t = i * 256 + w * 64 + lane;     // slot index
            int r = t >> 2, kq = t & 3;
            async16(A  + (size_t)(row0 + r) * KD + kt + kq * 8, &As[i * 256 + w * 64]);
            async16(Bt + (size_t)(col0 + r) * KD + kt + kq * 8, &Bs[i * 256 + w * 64]);
        }
        __syncthreads();

        bfrag a[4], b[4];
#pragma unroll
        for (int ri = 0; ri < 4; ri++)
            a[ri] = *(bfrag*)&As[(wr + ri * 16 + m16) * 4 + q];
#pragma unroll
        for (int ci = 0; ci < 4; ci++)
            b[ci] = *(bfrag*)&Bs[(wc + ci * 16 + m16) * 4 + q];
#pragma unroll
        for (int ri = 0; ri < 4; ri++)
#pragma unroll
            for (int ci = 0; ci < 4; ci++)
                acc[ri][ci] = __builtin_amdgcn_mfma_f32_16x16x32_bf16(
                    a[ri], b[ci], acc[ri][ci], 0, 0, 0);
        __syncthreads();
    }

    if (BF16OUT) {
        // 4 slabs of 32 rows; slab g fed by waves with wr==(g>>1)*64,
        // ri in {2(g&1), 2(g&1)+1}  (mapping validated in R4).
        unsigned int* Cb = (unsigned int*)Co;
        const int colc0 = col0 >> 1;            // complex col base
#pragma unroll
        for (int g = 0; g < 4; g++) {
            if (g) __syncthreads();
            if (wr == (g >> 1) * 64) {
                int gw = g & 1;
#pragma unroll
                for (int rj = 0; rj < 2; rj++) {
                    int ri = gw * 2 + rj;
#pragma unroll
                    for (int r4 = 0; r4 < 4; r4++) {
                        int rsl = rj * 16 + q * 4 + r4;      // slab row [0,32)
#pragma unroll
                        for (int ci = 0; ci < 4; ci++)
                            Ts[rsl * 132 + wc + ci * 16 + m16] = acc[ri][ci][r4];
                    }
                }
            }
            __syncthreads();
#pragma unroll
            for (int i = 0; i < 8; i++) {
                int flat = i * 256 + tid;            // 0..2047
                int r = flat >> 6, cu = flat & 63;   // 32 rows x 64 cplx
                float2 v = *(float2*)&Ts[r * 132 + cu * 2];
                Cb[(size_t)(row0 + g * 32 + r) * (ND / 2) + colc0 + cu] =
                    pk2(v.x, v.y);
            }
        }
    } else {
        // fp32 dword scatter: per (ri,r4,ci) 16 lanes = one full 64B line.
        float* Cf = (float*)Co;
#pragma unroll
        for (int ri = 0; ri < 4; ri++)
#pragma unroll
            for (int r4 = 0; r4 < 4; r4++) {
                int row = row0 + wr + ri * 16 + q * 4 + r4;
#pragma unroll
                for (int ci = 0; ci < 4; ci++) {
                    int col = col0 + wc + ci * 16 + m16;
                    Cf[(size_t)row * ND + col] = acc[ri][ci][r4];
                }
            }
    }
}

// ------- scan phase 1: chunk-final states only (bu is packed bf16) ----------
__global__ __launch_bounds__(512) void scan_states_kernel(
    const unsigned int* __restrict__ bu, const float2* __restrict__ lam,
    float2* __restrict__ states)
{
    int n = threadIdx.x;
    int b = blockIdx.x >> 6;
    int c = blockIdx.x & 63;
    float2 lm = lam[n];
    float xr = 0.f, xi = 0.f;
    bool fwd = (n < 256);
    int l0 = fwd ? (c * CHUNK) : (c * CHUNK + CHUNK - 1);
    const unsigned int* p = bu + ((size_t)b * L_SEQ + l0) * 512 + n;
    ptrdiff_t step = fwd ? 512 : -512;
#pragma unroll 8
    for (int t = 0; t < CHUNK; t++) {
        float2 v = unpk2(*p);
        float nr = lm.x * xr - lm.y * xi + v.x;
        float ni = lm.x * xi + lm.y * xr + v.y;
        xr = nr; xi = ni;
        p += step;
    }
    states[((size_t)b * NCHUNK + c) * 512 + n] = make_float2(xr, xi);
}

// ---------------- scan phase 2: combine chunk states -> exclusive carries ---
__global__ __launch_bounds__(512) void scan_combine_kernel(
    const float2* __restrict__ states, float2* __restrict__ carries,
    const float2* __restrict__ lam)
{
    int n = threadIdx.x;
    int b = blockIdx.x;
    float2 lm = lam[n];
    float ar = lm.x, ai = lm.y;          // lam^64 by 6 squarings
#pragma unroll
    for (int i = 0; i < 6; i++) {
        float nr = ar * ar - ai * ai;
        ai = 2.f * ar * ai;
        ar = nr;
    }
    float cr = 0.f, ci = 0.f;
    bool fwd = (n < 256);
    if (fwd) {
        for (int c = 0; c < NCHUNK; c++) {
            size_t idx = ((size_t)b * NCHUNK + c) * 512 + n;
            carries[idx] = make_float2(cr, ci);
            float2 s = states[idx];
            float nr = ar * cr - ai * ci + s.x;
            float ni = ar * ci + ai * cr + s.y;
            cr = nr; ci = ni;
        }
    } else {
        for (int c = NCHUNK - 1; c >= 0; c--) {
            size_t idx = ((size_t)b * NCHUNK + c) * 512 + n;
            carries[idx] = make_float2(cr, ci);
            float2 s = states[idx];
            float nr = ar * cr - ai * ci + s.x;
            float ni = ar * ci + ai * cr + s.y;
            cr = nr; ci = ni;
        }
    }
}

// -------- scan phase 3: re-scan seeded with carry + mask, in place ----------
// x_t = lam * x_{t-1} + bu_t with x_init = carry  ==  local scan + lam^(t+1)*carry.
__global__ __launch_bounds__(512) void scan_apply_kernel(
    unsigned int* __restrict__ bu, const float2* __restrict__ carries,
    const float2* __restrict__ lam, const int* __restrict__ lengths)
{
    int n = threadIdx.x;
    int b = blockIdx.x >> 6;
    int c = blockIdx.x & 63;
    int len = lengths[b];
    float2 lm = lam[n];
    float2 cy = carries[((size_t)b * NCHUNK + c) * 512 + n];
    bool fwd = (n < 256);
    int l0 = fwd ? (c * CHUNK) : (c * CHUNK + CHUNK - 1);
    int dl = fwd ? 1 : -1;
    unsigned int* p = bu + ((size_t)b * L_SEQ + l0) * 512 + n;
    ptrdiff_t step = fwd ? 512 : -512;
    float xr = cy.x, xi = cy.y;
    int l = l0;
#pragma unroll 8
    for (int t = 0; t < CHUNK; t++) {
        float2 v = unpk2(*p);
        float nr = lm.x * xr - lm.y * xi + v.x;
        float ni = lm.x * xi + lm.y * xr + v.y;
        xr = nr; xi = ni;
        *p = (l >= len) ? 0u : pk2(xr, xi);
        p += step; l += dl;
    }
}

// ---------------- launch ----------------------------------------------------
extern "C" void kernel_launch(void* const* d_in, const int* in_sizes, int n_in,
                              void* d_out, int out_size, void* d_ws, size_t ws_size,
                              hipStream_t stream)
{
    const float* u        = (const float*)d_in[0];   // (8,4096,512)
    const int*   lengths  = (const int*)  d_in[1];   // (8,)
    const float* nu_log   = (const float*)d_in[2];   // (512,)
    const float* theta_log= (const float*)d_in[3];   // (512,)
    const float* B        = (const float*)d_in[4];   // (512,512,2) == (512 x 1024)
    const float* C        = (const float*)d_in[5];   // (2,512,512)
    float* y = (float*)d_out;                        // (8,4096,512)

    char* wp = (char*)d_ws;
    float2* lam     = (float2*)wp;  wp += 4096;
    float2* states  = (float2*)wp;  wp += (size_t)BSZQ * NCHUNK * 512 * 8;  // 2 MB
    float2* carries = (float2*)wp;  wp += (size_t)BSZQ * NCHUNK * 512 * 8;  // 2 MB
    unsigned int* bu = (unsigned int*)wp; wp += (size_t)ROWS * 512 * 4;     // 64 MB packed bf16
    unsigned short* ub = (unsigned short*)wp; wp += (size_t)ROWS * 512 * 2; // 32 MB
    unsigned short* Bt = (unsigned short*)wp; wp += (size_t)NC1 * KC1 * 2;  // 1 MB
    unsigned short* Dt = (unsigned short*)wp; wp += (size_t)NC2 * KC2 * 2;  // 1 MB

    lru_lam_kernel<<<1, 512, 0, stream>>>(nu_log, theta_log, lam);
    conv_mask_kernel<<<8192, 256, 0, stream>>>(u, lengths, ub);
    prep_Bt_kernel<<<2048, 256, 0, stream>>>(B, Bt);
    prep_Dt_kernel<<<2048, 256, 0, stream>>>(C, Dt);

    // GEMM1: bu(packed bf16) = ub @ Bt^T  (mask folded into ub)
    {
        dim3 grid(ROWS / 128, NC1 / 128);   // (256, 8)
        mfma_gemm_async<KC1, NC1, true><<<grid, 256, 0, stream>>>(ub, Bt, bu);
    }

    scan_states_kernel<<<BSZQ * NCHUNK, 512, 0, stream>>>(bu, lam, states);
    scan_combine_kernel<<<BSZQ, 512, 0, stream>>>(states, carries, lam);
    scan_apply_kernel<<<BSZQ * NCHUNK, 512, 0, stream>>>(bu, carries, lam, lengths);

    // GEMM2: y = bu(=x, packed bf16) @ Dt^T, fp32 out
    {
        dim3 grid(ROWS / 128, NC2 / 128);   // (256, 4)
        mfma_gemm_async<KC2, NC2, false><<<grid, 256, 0, stream>>>(
            (const unsigned short*)bu, Dt, y);
    }
}